// Round 5
// baseline (2071.631 us; speedup 1.0000x reference)
//
#include <hip/hip_runtime.h>
#include <math.h>

// SwinDecoder on MI355X. Round 12: barrier-free mlp_fused.
// R7-R11 evidence: the staged-LDS-weights structure pins mlp at ~158-160us
// regardless of LDS size, bank conflicts, VALU count, tile size, or manual
// pipelining (R11: +dbuf lost a resident block -> 202us; usable LDS/CU is
// ~144-147KB, not 160K). 62% of time no pipe issues = barrier convoys.
// Fix: weights precomputed in MFMA-fragment-interleaved layout (frag =
// contiguous 1024B, lane offset = lane*16, same trick as bias_precompute);
// each wave global_load_dwordx4's B-fragments directly to registers -
// perfectly coalesced, L1/L2-hot, NO shared staging, NO barriers. Waves
// fully independent after LN2; compiler pipelines loads across phases.
// A/h stay in wave-private rotation-swizzled AH (proven R8-R9).
// LDS 27.6KB. One __syncthreads total (b1 bias stage).
// Attention path unchanged from R6/R7.
// ws layout (bytes):
//   e        : 0          .. 50,331,648   fp32 [65536][192]
//   bias_il  : 50,331,648 .. 51,118,080   bf16 interleaved [4][6][16384]
//   wt       : 51,904,512 .. 55,541,760   bf16 weights (4 layers + pe + rec)
//              per layer: qkv_t 110592 | proj_t 36864 | fc1_il | fc2_il shorts
//   stage    : 55,541,760 .. (attention chunk only; 1920 B/row)

#define CCH 192
#define HEADS 6

typedef __attribute__((ext_vector_type(8))) short bf16x8;
typedef __attribute__((ext_vector_type(4))) float f32x4;

__device__ __forceinline__ unsigned short f2bf(float f){
    union { float f; unsigned int u; } x; x.f = f;
    unsigned int r = (x.u + 0x7fffu + ((x.u >> 16) & 1u)) >> 16;
    return (unsigned short)r;
}
__device__ __forceinline__ float bf2f(unsigned short h){
    union { unsigned int u; float f; } x; x.u = ((unsigned int)h)<<16;
    return x.f;
}

__device__ __forceinline__ void async16(const void* g, void* l){
    __builtin_amdgcn_global_load_lds(
        (const __attribute__((address_space(1))) void*)g,
        (__attribute__((address_space(3))) void*)l, 16, 0, 0);
}

__device__ __forceinline__ ushort4 cvt4(float4 v){
    ushort4 r; r.x=f2bf(v.x); r.y=f2bf(v.y); r.z=f2bf(v.z); r.w=f2bf(v.w);
    return r;
}

__device__ __forceinline__ int zone_z(int z){ return z<30?0:(z<31?1:2); }
__device__ __forceinline__ int zone_hw(int h){ return h<24?0:(h<28?1:2); }

// gelu with A&S 7.1.26 erf: |err| <= 1.5e-7, branchless, 1 v_exp + 1 v_rcp.
__device__ __forceinline__ float gelu_f(float v){
    float xx = v*0.70710678118654752f;
    float ax = fabsf(xx);
    float ti = __builtin_amdgcn_rcpf(fmaf(0.3275911f, ax, 1.f));
    float p  = fmaf(ti, 1.061405429f, -1.453152027f);
    p = fmaf(ti, p, 1.421413741f);
    p = fmaf(ti, p, -0.284496736f);
    p = fmaf(ti, p, 0.254829592f);
    p = p * ti;
    float ex = __expf(-ax*ax);
    float er = fmaf(-p, ex, 1.f);
    er = __builtin_copysignf(er, xx);
    return 0.5f*v*(1.f + er);
}

// ---------------- weight convert+transpose: w[K][N] fp32 -> wt[N][K] bf16 --
__global__ void wt_convert(const float* __restrict__ w, unsigned short* __restrict__ wt,
                           int K, int N)
{
    int idx = blockIdx.x*256 + threadIdx.x;
    if (idx >= K*N) return;
    int n = idx / K, k = idx - n*K;
    wt[idx] = f2bf(w[(size_t)k*N + n]);
}

// ---------------- plain fp32 -> bf16 convert -------------------------------
__global__ void pe_conv(const float* __restrict__ w, unsigned short* __restrict__ o, int n)
{
    int i = blockIdx.x*256 + threadIdx.x;
    if (i < n) o[i] = f2bf(w[i]);
}

// ---- fc1 fp32 [768 rows k][192... actually [K=192][N=768] row-major ------
// -> MFMA-fragment-interleaved bf16: frag f = (c*6+kq)*12+nt, 1024B each,
// lane offset lane*16. Lane(quad,l16) holds w[k = kq*32+quad*8+s][n =
// c*192+nt*16+l16] for s=0..7 (k within ks*64 block; kq=ks*2+half).
__global__ void fc1_il_convert(const float* __restrict__ w, unsigned short* __restrict__ o)
{
    int tid = blockIdx.x*256 + threadIdx.x;      // < 147456
    int f = tid >> 9;            // frag 0..287
    int r = tid & 511;
    int lane = r >> 3, s = r & 7;
    int nt = f % 12, g = f / 12; // g = c*6 + kq
    int kq = g % 6, c = g / 6;
    int n = c*192 + nt*16 + (lane & 15);
    int k = kq*32 + (lane >> 4)*8 + s;
    o[tid] = f2bf(w[(size_t)k*768 + n]);
}

// ---- fc2 fp32 [K=768][N=192] row-major -> interleaved; frag f as above;
// lane holds w[k2 = c*192+kq*32+quad*8+s][n2 = nt*16+l16].
__global__ void fc2_il_convert(const float* __restrict__ w, unsigned short* __restrict__ o)
{
    int tid = blockIdx.x*256 + threadIdx.x;      // < 147456
    int f = tid >> 9;
    int r = tid & 511;
    int lane = r >> 3, s = r & 7;
    int nt = f % 12, g = f / 12;
    int kq = g % 6, c = g / 6;
    int k2 = c*192 + kq*32 + (lane >> 4)*8 + s;
    int n2 = nt*16 + (lane & 15);
    o[tid] = f2bf(w[(size_t)k2*192 + n2]);
}

// ---- rel-pos bias -> bf16 in MFMA-interleaved layout ----------------------
__global__ void bias_precompute(const float* __restrict__ rpb,
                                unsigned short* __restrict__ bias_il)
{
    int d = blockIdx.x / HEADS, head = blockIdx.x % HEADS;
    int n = threadIdx.x;
    int i1 = n>>6, j1 = (n>>3)&7, k1 = n&7;
    const float* rp = rpb + d*675*HEADS;
    unsigned short* out = bias_il + (size_t)blockIdx.x*16384;
    int rbase = (n>>4)*2048 + (n&15)*8;
    for (int m = 0; m < 128; ++m){
        int i2 = m>>6, j2 = (m>>3)&7, k2 = m&7;
        int idx = (i1-i2+1)*225 + (j1-j2+7)*15 + (k1-k2+7);
        int off = rbase + (m>>5)*512 + ((m>>3)&3)*128 + (m&7);
        out[off] = f2bf(rp[idx*HEADS + head]);
    }
}

// ---------------- patch embed via MFMA, LN fused in epilogue ---------------
__global__ __launch_bounds__(256) void patch_embed_mfma(
    const float* __restrict__ x, const unsigned short* __restrict__ pwb,
    const float* __restrict__ pe_b, const float* __restrict__ gg,
    const float* __restrict__ bb, float* __restrict__ e)
{
    __shared__ __align__(16) unsigned short As[64*132];
    __shared__ __align__(16) unsigned short Bs[96*132];
    int t = threadIdx.x;
    int wave = t>>6, lane = t&63, quad = lane>>4, l16 = lane&15;
    int m0 = blockIdx.x*64;

    {
        int row = t & 63, cg = (t>>6)*8;
        int pos = m0 + row;
        int w = pos&31, h=(pos>>5)&31, z=(pos>>10)&31, b=pos>>15;
        #pragma unroll
        for (int cc=0; cc<8; ++cc){
            int chunk = cg + cc;
            int c = chunk>>3, i=(chunk>>2)&1, j=chunk&3;
            float4 v = *(const float4*)&x[ (((size_t)(b*4+c)*64 + (z*2+i))*128 + (h*4+j))*128 + w*4 ];
            *(ushort4*)&As[row*132 + chunk*4] = cvt4(v);
        }
    }

    f32x4 acc[12] = {};
    #pragma unroll
    for (int ph = 0; ph < 2; ++ph){
        if (ph) __syncthreads();
        #pragma unroll
        for (int it=0; it<6; ++it){
            int g = it*256 + t;
            int row = g >> 4, c8 = g & 15;
            const unsigned short* src = pwb + ((size_t)(ph*96+row))*128 + c8*8;
            uint4 u = *(const uint4*)src;
            unsigned short* dst = &Bs[row*132 + c8*8];
            *(uint2*)dst       = make_uint2(u.x, u.y);
            *(uint2*)(dst+4)   = make_uint2(u.z, u.w);
        }
        __syncthreads();
        #pragma unroll
        for (int ks=0; ks<4; ++ks){
            bf16x8 af = *(const bf16x8*)&As[(wave*16 + l16)*132 + ks*32 + quad*8];
            #pragma unroll
            for (int nt=0; nt<6; ++nt){
                bf16x8 bf = *(const bf16x8*)&Bs[(nt*16 + l16)*132 + ks*32 + quad*8];
                acc[ph*6+nt] = __builtin_amdgcn_mfma_f32_16x16x32_bf16(
                    af, bf, acc[ph*6+nt], 0, 0, 0);
            }
        }
    }

    float pb[12], gv[12], bv[12];
    #pragma unroll
    for (int nt=0; nt<12; ++nt){
        int col = nt*16 + l16;
        pb[nt] = pe_b[col]; gv[nt] = gg[col]; bv[nt] = bb[col];
    }
    #pragma unroll
    for (int r=0; r<4; ++r){
        int row = wave*16 + quad*4 + r;
        int pos = m0 + row;
        float sv[12], s1 = 0.f, s2 = 0.f;
        #pragma unroll
        for (int nt=0; nt<12; ++nt){
            float v = acc[nt][r] + pb[nt];
            sv[nt] = v; s1 += v; s2 += v*v;
        }
        #pragma unroll
        for (int off=1; off<16; off<<=1){
            s1 += __shfl_xor(s1, off); s2 += __shfl_xor(s2, off);
        }
        float mean = s1*(1.f/192.f);
        float rstd = rsqrtf(s2*(1.f/192.f) - mean*mean + 1e-5f);
        #pragma unroll
        for (int nt=0; nt<12; ++nt){
            int col = nt*16 + l16;
            e[(size_t)pos*CCH + col] = (sv[nt]-mean)*rstd*gv[nt] + bv[nt];
        }
    }
}

// ---------------- reconstruction via MFMA ----------------------------------
__global__ __launch_bounds__(256) void recon_mfma(
    const float* __restrict__ e, const unsigned short* __restrict__ rwt,
    const float* __restrict__ rec_b, float* __restrict__ out)
{
    __shared__ __align__(16) unsigned short As[64*196];
    __shared__ __align__(16) unsigned short Bs[64*196];
    int t = threadIdx.x;
    int wave = t>>6, lane = t&63, quad = lane>>4, l16 = lane&15;
    int m0 = blockIdx.x*64;

    #pragma unroll
    for (int it=0; it<12; ++it){
        int g = it*256 + t;
        int row = g/48, c4 = g - row*48;
        float4 v = *(const float4*)&e[(size_t)(m0+row)*CCH + c4*4];
        *(ushort4*)&As[row*196 + c4*4] = cvt4(v);
    }

    f32x4 acc[8] = {};
    #pragma unroll
    for (int ph = 0; ph < 2; ++ph){
        if (ph) __syncthreads();
        #pragma unroll
        for (int it=0; it<6; ++it){
            int g = it*256 + t;
            int row = g/24, c8 = g - row*24;
            const unsigned short* src = rwt + ((size_t)(ph*64+row))*192 + c8*8;
            uint4 u = *(const uint4*)src;
            unsigned short* dst = &Bs[row*196 + c8*8];
            *(uint2*)dst     = make_uint2(u.x, u.y);
            *(uint2*)(dst+4) = make_uint2(u.z, u.w);
        }
        __syncthreads();
        #pragma unroll
        for (int ks=0; ks<6; ++ks){
            bf16x8 af = *(const bf16x8*)&As[(wave*16 + l16)*196 + ks*32 + quad*8];
            #pragma unroll
            for (int nt=0; nt<4; ++nt){
                bf16x8 bf = *(const bf16x8*)&Bs[(nt*16 + l16)*196 + ks*32 + quad*8];
                acc[ph*4+nt] = __builtin_amdgcn_mfma_f32_16x16x32_bf16(
                    af, bf, acc[ph*4+nt], 0, 0, 0);
            }
        }
    }

    #pragma unroll
    for (int nt=0; nt<8; ++nt){
        int col = nt*16 + l16;
        int o = col>>5, i = (col>>4)&1, j = (col>>2)&3, k = col&3;
        float rb = rec_b[o];
        #pragma unroll
        for (int r=0; r<4; ++r){
            int pos = m0 + wave*16 + quad*4 + r;
            int w = pos&31, h=(pos>>5)&31, z=(pos>>10)&31, b=pos>>15;
            out[ (((size_t)(b*4+o)*64 + (z*2+i))*128 + (h*4+j))*128 + (w*4+k) ]
                = acc[nt][r] + rb;
        }
    }
}

// ---------------- LayerNorm -> bf16; window gather (ln1 path) --------------
__global__ __launch_bounds__(192) void ln_kernel(
    const float* __restrict__ in, unsigned short* __restrict__ outp,
    const float* __restrict__ gg, const float* __restrict__ bb,
    int shifted, int row0)
{
    int tid = threadIdx.x;
    int r = blockIdx.x + row0;
    int wb = r>>7, tok = r&127;
    int b = wb>>8, nw = wb&255;
    int zs = (nw>>4)*2 + (tok>>6);
    int hs = ((nw>>2)&3)*8 + ((tok>>3)&7);
    int ws = (nw&3)*8 + (tok&7);
    int z,h,w;
    if (shifted){ z=(zs+1)&31; h=(hs+4)&31; w=(ws+4)&31; }
    else        { z=zs; h=hs; w=ws; }
    int src = ((b*32+z)*32+h)*32+w;
    float val = in[(size_t)src*CCH + tid];
    float s = val, s2 = val*val;
    for (int off=32; off>=1; off>>=1){ s += __shfl_xor(s,off); s2 += __shfl_xor(s2,off); }
    __shared__ float red[2][3];
    if ((tid&63)==0){ red[0][tid>>6]=s; red[1][tid>>6]=s2; }
    __syncthreads();
    float sum = red[0][0]+red[0][1]+red[0][2];
    float sq  = red[1][0]+red[1][1]+red[1][2];
    float mean = sum*(1.f/192.f);
    float rstd = rsqrtf(sq*(1.f/192.f) - mean*mean + 1e-5f);
    outp[(size_t)blockIdx.x*CCH + tid] = f2bf((val-mean)*rstd*gg[tid] + bb[tid]);
}

// ---------------- bf16 MFMA GEMM ------------------------------------------
// MODE 2: window-reverse residual add (fp32 e).
// MODE 5: qkv split: n<384 -> Ch[m][384] (Q|K); n>=384 -> Vout[win][d][tok].
template<int MODE>
__global__ __launch_bounds__(256) void gemm_mfma(
    const unsigned short* __restrict__ A, const unsigned short* __restrict__ Bt,
    const float* __restrict__ bias, void* __restrict__ Cout,
    unsigned short* __restrict__ Vout,
    int N, int K, int shifted, int row0)
{
    __shared__ __align__(16) unsigned short As[128*32];
    __shared__ __align__(16) unsigned short Bs[64*32];
    int t = threadIdx.x;
    int wave = t >> 6, lane = t & 63;
    int quad = lane >> 4, l16 = lane & 15;
    int m0 = blockIdx.y * 128, n0 = blockIdx.x * 64;

    f32x4 acc[2][4] = {};
    int ldrow = lane >> 2;
    int ldk   = (lane & 3) * 8;

    for (int k0 = 0; k0 < K; k0 += 32){
        #pragma unroll
        for (int s2 = 0; s2 < 2; ++s2){
            int s = wave*2 + s2;
            async16(A + (size_t)(m0 + s*16 + ldrow)*K + k0 + ldk, &As[s*512]);
        }
        async16(Bt + (size_t)(n0 + wave*16 + ldrow)*K + k0 + ldk, &Bs[wave*512]);
        __syncthreads();
        bf16x8 af[2], bfr[4];
        #pragma unroll
        for (int mt=0; mt<2; ++mt)
            af[mt] = *(const bf16x8*)&As[(wave*32 + mt*16 + l16)*32 + quad*8];
        #pragma unroll
        for (int nt=0; nt<4; ++nt)
            bfr[nt] = *(const bf16x8*)&Bs[(nt*16 + l16)*32 + quad*8];
        #pragma unroll
        for (int mt=0; mt<2; ++mt)
            #pragma unroll
            for (int nt=0; nt<4; ++nt)
                acc[mt][nt] = __builtin_amdgcn_mfma_f32_16x16x32_bf16(
                    af[mt], bfr[nt], acc[mt][nt], 0, 0, 0);
        __syncthreads();
    }

    float* Cf = (float*)Cout;
    unsigned short* Ch = (unsigned short*)Cout;
    #pragma unroll
    for (int mt=0; mt<2; ++mt){
        #pragma unroll
        for (int nt=0; nt<4; ++nt){
            int n = n0 + nt*16 + l16;
            if (MODE==5 && n0 + nt*16 >= 384){
                int d = n - 384;
                int win = m0 >> 7;
                int tok0 = wave*32 + mt*16 + quad*4;
                float bn = bias[n];
                ushort4 vv;
                vv.x = f2bf(acc[mt][nt][0]+bn); vv.y = f2bf(acc[mt][nt][1]+bn);
                vv.z = f2bf(acc[mt][nt][2]+bn); vv.w = f2bf(acc[mt][nt][3]+bn);
                *(ushort4*)&Vout[((size_t)win*192 + d)*128 + tok0] = vv;
                continue;
            }
            #pragma unroll
            for (int r=0; r<4; ++r){
                int m = m0 + wave*32 + mt*16 + quad*4 + r;
                float v = acc[mt][nt][r] + bias[n];
                if (MODE==5){
                    Ch[(size_t)m*384 + n] = f2bf(v);
                } else {
                    int mg = m + row0;
                    int wb = mg>>7, tok = mg&127;
                    int b = wb>>8, nw = wb&255;
                    int zs = (nw>>4)*2 + (tok>>6);
                    int hs = ((nw>>2)&3)*8 + ((tok>>3)&7);
                    int ws = (nw&3)*8 + (tok&7);
                    int z,h,w;
                    if (shifted){ z=(zs+1)&31; h=(hs+4)&31; w=(ws+4)&31; }
                    else        { z=zs; h=hs; w=ws; }
                    Cf[(size_t)(((b*32+z)*32+h)*32+w)*CCH + n] += v;
                }
            }
        }
    }
}

// ---------------- fused MLP: ln2 + fc1 + gelu + fc2 + residual -------------
// R12: barrier-free. 64 rows/block, 4 waves, wave-private 16 rows.
// B-fragments loaded straight from global (fragment-interleaved layout,
// 1024B contiguous per fragment, lane*16 offset -> one global_load_dwordx4
// per fragment, fully coalesced, L1/L2-hot). No shared weight staging, no
// per-phase barriers; waves fully independent after LN2. A (LN out) in
// registers (af[6]); h round-trips through wave-private rotation-swizzled
// AH (transpose C-layout -> A-layout). One __syncthreads (b1 stage).
// LDS: AH 24K + b1s 3K = 27.6 KB.
__global__ __launch_bounds__(256) void mlp_fused(
    float* __restrict__ e,
    const unsigned short* __restrict__ w1il, const float* __restrict__ b1,
    const unsigned short* __restrict__ w2il, const float* __restrict__ b2,
    const float* __restrict__ g2, const float* __restrict__ be2)
{
    __shared__ __align__(16) unsigned short AH[4*3072];
    __shared__ float b1s[768];
    int t = threadIdx.x;
    int wave = t>>6, lane = t&63, quad = lane>>4, l16 = lane&15;
    int m0 = blockIdx.x*64;
    unsigned short* AHw = AH + wave*3072;

    // stage b1 biases to LDS (read per-lane in gelu)
    b1s[t] = b1[t]; b1s[t+256] = b1[t+256]; b1s[t+512] = b1[t+512];

    // ---- LN2 over the wave's 16 rows (lane-strided, 64-lane butterfly) ----
    float g0 = g2[lane],  gA = g2[lane+64],  gB = g2[lane+128];
    float c0 = be2[lane], cA = be2[lane+64], cB = be2[lane+128];
    int lo = lane>>3, lsub = lane&7;
    for (int rr=0; rr<16; ++rr){
        const float* row = e + (size_t)(m0 + wave*16 + rr)*CCH;
        float v0 = row[lane], v1 = row[lane+64], v2 = row[lane+128];
        float s = v0+v1+v2, q = v0*v0+v1*v1+v2*v2;
        #pragma unroll
        for (int o=1;o<64;o<<=1){ s += __shfl_xor(s,o); q += __shfl_xor(q,o); }
        float mean = s*(1.f/192.f);
        float rstd = rsqrtf(q*(1.f/192.f) - mean*mean + 1e-5f);
        AHw[(lo     )*128 + ((rr+lo    )&15)*8 + lsub] = f2bf((v0-mean)*rstd*g0 + c0);
        AHw[(lo +  8)*128 + ((rr+lo+ 8 )&15)*8 + lsub] = f2bf((v1-mean)*rstd*gA + cA);
        AHw[(lo + 16)*128 + ((rr+lo+16 )&15)*8 + lsub] = f2bf((v2-mean)*rstd*gB + cB);
    }

    // ---- hoist A fragments to registers (wave-private, in-order LDS) ----
    bf16x8 af[6];
    #pragma unroll
    for (int k3=0; k3<6; ++k3){
        int g = k3*4 + quad;
        af[k3] = *(const bf16x8*)&AHw[g*128 + ((l16+g)&15)*8];
    }
    __syncthreads();   // b1s visibility (the only block barrier)

    const bf16x8* W1 = (const bf16x8*)w1il;
    const bf16x8* W2 = (const bf16x8*)w2il;

    f32x4 acc2[12] = {};
    for (int c = 0; c < 4; ++c){
        // ---- fc1 chunk: h[.,c*192..+192) = A @ W1[c] (frags from global) --
        f32x4 acc1[12] = {};
        #pragma unroll
        for (int kq = 0; kq < 6; ++kq){
            const bf16x8* base = W1 + ((size_t)(c*6 + kq)*12)*64 + lane;
            bf16x8 a = af[kq];
            #pragma unroll
            for (int nt=0; nt<12; ++nt){
                bf16x8 bf = base[nt*64];
                acc1[nt] = __builtin_amdgcn_mfma_f32_16x16x32_bf16(
                    a, bf, acc1[nt], 0, 0, 0);
            }
        }
        // ---- gelu + write h chunk to wave-private LDS (rotated layout) ----
        #pragma unroll
        for (int nt=0; nt<12; ++nt){
            float bias1 = b1s[c*192 + nt*16 + l16];
            int ko = nt*2 + (l16>>3), sb = l16&7;
            #pragma unroll
            for (int r=0; r<4; ++r){
                float v = gelu_f(acc1[nt][r] + bias1);
                AHw[ko*128 + ((quad*4+r+ko)&15)*8 + sb] = f2bf(v);
            }
        }
        // ---- fc2 partial: acc2 += h_chunk @ W2[c] (frags from global) ----
        #pragma unroll
        for (int kq = 0; kq < 6; ++kq){
            int g = kq*4 + quad;
            bf16x8 a = *(const bf16x8*)&AHw[g*128 + ((l16+g)&15)*8];
            const bf16x8* base = W2 + ((size_t)(c*6 + kq)*12)*64 + lane;
            #pragma unroll
            for (int nt=0; nt<12; ++nt){
                bf16x8 bf = base[nt*64];
                acc2[nt] = __builtin_amdgcn_mfma_f32_16x16x32_bf16(
                    a, bf, acc2[nt], 0, 0, 0);
            }
        }
    }

    // ---- epilogue: e += fc2 out + bias (residual re-read, L2-hot) ----
    #pragma unroll
    for (int nt=0; nt<12; ++nt){
        int n = nt*16 + l16;
        float bias2 = b2[n];
        #pragma unroll
        for (int r=0; r<4; ++r){
            size_t idx = (size_t)(m0 + wave*16 + quad*4 + r)*CCH + n;
            e[idx] += acc2[nt][r] + bias2;
        }
    }
}

// ---------------- MFMA attention (unchanged from R6) -----------------------
__global__ __launch_bounds__(256) void attn_mfma(
    const unsigned short* __restrict__ qk,
    const unsigned short* __restrict__ vbuf,
    unsigned short* __restrict__ obuf,
    const unsigned short* __restrict__ bias_layer,
    int shifted, int wb0)
{
    __shared__ __align__(16) unsigned short Ks[4096];
    __shared__ __align__(16) unsigned short Vt[4096];
    __shared__ __align__(16) unsigned short Ps[16384];
    __shared__ float linv[128];
    __shared__ int grp[128];

    int t = threadIdx.x;
    int wave = t >> 6, lane = t & 63;
    int quad = lane >> 4, l16 = lane & 15;
    int wb = blockIdx.x / HEADS;
    int head = blockIdx.x % HEADS;
    int nw = (wb + wb0) & 255;

    const unsigned short* qkw = qk + (size_t)wb*128*384;

    bf16x8 af[2];
    #pragma unroll
    for (int mt=0; mt<2; ++mt)
        af[mt] = *(const bf16x8*)(qkw + (size_t)(wave*32 + mt*16 + l16)*384 + head*32 + quad*8);

    {
        int chunk = lane >> 4, low = lane & 15;
        #pragma unroll
        for (int i=0; i<2; ++i){
            int j = wave*2 + i;
            async16(qkw + (size_t)(j*16 + low)*384 + 192 + head*32 + chunk*8, &Ks[j*512]);
        }
        const unsigned short* vb = vbuf + ((size_t)wb*192 + head*32)*128;
        #pragma unroll
        for (int i=0; i<2; ++i){
            int j = wave*2 + i; int dgrp = j>>2, tg = j&3;
            async16(vb + (size_t)(dgrp*16 + low)*128 + tg*32 + chunk*8, &Vt[j*512]);
        }
        const unsigned short* bsrc = bias_layer + (size_t)head*16384;
        #pragma unroll
        for (int i=0; i<8; ++i){
            int j = wave*8 + i;
            async16(bsrc + j*512 + lane*8, &Ps[j*512]);
        }
    }
    if (t < 128 && shifted){
        int zs = (nw>>4)*2 + (t>>6);
        int hs = ((nw>>2)&3)*8 + ((t>>3)&7);
        int ws = (nw&3)*8 + (t&7);
        grp[t] = zone_z(zs)*9 + zone_hw(hs)*3 + zone_hw(ws);
    }
    __syncthreads();

    f32x4 sacc[2][8] = {};
    #pragma unroll
    for (int nt=0; nt<8; ++nt){
        bf16x8 bfr = *(const bf16x8*)&Ks[nt*512 + quad*128 + l16*8];
        sacc[0][nt] = __builtin_amdgcn_mfma_f32_16x16x32_bf16(af[0], bfr, sacc[0][nt], 0,0,0);
        sacc[1][nt] = __builtin_amdgcn_mfma_f32_16x16x32_bf16(af[1], bfr, sacc[1][nt], 0,0,0);
    }

    const float scale = 0.17677669529663689f;
    #pragma unroll
    for (int mt=0; mt<2; ++mt){
        #pragma unroll
        for (int r=0; r<4; ++r){
            int row = wave*32 + mt*16 + quad*4 + r;
            int rbase = (wave*2+mt)*2048 + (quad*4+r)*8;
            int myg = shifted ? grp[row] : 0;
            float sv[8]; int offv[8];
            float mloc = -1e30f;
            #pragma unroll
            for (int nt=0; nt<8; ++nt){
                int off = rbase + (nt>>1)*512 + (((nt&1)<<1) + (l16>>3))*128 + (l16&7);
                offv[nt] = off;
                float s = sacc[mt][nt][r]*scale + bf2f(Ps[off]);
                if (shifted && grp[nt*16+l16] != myg) s -= 100.f;
                sv[nt] = s;
                mloc = fmaxf(mloc, s);
            }
            #pragma unroll
            for (int off=1; off<16; off<<=1) mloc = fmaxf(mloc, __shfl_xor(mloc, off));
            float lloc = 0.f;
            #pragma unroll
            for (int nt=0; nt<8; ++nt){
                float p = __expf(sv[nt]-mloc);
                sv[nt] = p; lloc += p;
            }
            #pragma unroll
            for (int off=1; off<16; off<<=1) lloc += __shfl_xor(lloc, off);
            #pragma unroll
            for (int nt=0; nt<8; ++nt)
                Ps[offv[nt]] = f2bf(sv[nt]);
            if (l16==0) linv[row] = 1.f/lloc;
        }
    }

    f32x4 oacc[2][2] = {};
    #pragma unroll
    for (int ks=0; ks<4; ++ks){
        bf16x8 av0 = *(const bf16x8*)&Vt[         ks*512 + quad*128 + l16*8];
        bf16x8 av1 = *(const bf16x8*)&Vt[ 2048 +  ks*512 + quad*128 + l16*8];
        bf16x8 pf0 = *(const bf16x8*)&Ps[(wave*2+0)*2048 + ks*512 + quad*128 + l16*8];
        bf16x8 pf1 = *(const bf16x8*)&Ps[(wave*2+1)*2048 + ks*512 + quad*128 + l16*8];
        oacc[0][0] = __builtin_amdgcn_mfma_f32_16x16x32_bf16(av0, pf0, oacc[0][0], 0,0,0);
        oacc[0][1] = __builtin_amdgcn_mfma_f32_16x16x32_bf16(av1, pf0, oacc[0][1], 0,0,0);
        oacc[1][0] = __builtin_amdgcn_mfma_f32_16x16x32_bf16(av0, pf1, oacc[1][0], 0,0,0);
        oacc[1][1] = __builtin_amdgcn_mfma_f32_16x16x32_bf16(av1, pf1, oacc[1][1], 0,0,0);
    }

    #pragma unroll
    for (int mt=0; mt<2; ++mt){
        int token = wave*32 + mt*16 + l16;
        float inv = linv[token];
        unsigned short* dst = obuf + (size_t)(wb*128+token)*CCH + head*32;
        #pragma unroll
        for (int dt=0; dt<2; ++dt){
            ushort4 v4;
            v4.x = f2bf(oacc[mt][dt][0]*inv);
            v4.y = f2bf(oacc[mt][dt][1]*inv);
            v4.z = f2bf(oacc[mt][dt][2]*inv);
            v4.w = f2bf(oacc[mt][dt][3]*inv);
            *(ushort4*)&dst[dt*16 + quad*4] = v4;
        }
    }
}

extern "C" void kernel_launch(void* const* d_in, const int* in_sizes, int n_in,
                              void* d_out, int out_size, void* d_ws, size_t ws_size,
                              hipStream_t stream) {
    const float* x       = (const float*)d_in[0];
    const float* pe_w    = (const float*)d_in[1];
    const float* pe_b    = (const float*)d_in[2];
    const float* pe_ln_g = (const float*)d_in[3];
    const float* pe_ln_b = (const float*)d_in[4];
    const float* ln1_g   = (const float*)d_in[5];
    const float* ln1_b   = (const float*)d_in[6];
    const float* qkv_w   = (const float*)d_in[7];
    const float* qkv_b   = (const float*)d_in[8];
    const float* proj_w  = (const float*)d_in[9];
    const float* proj_b  = (const float*)d_in[10];
    const float* rpb     = (const float*)d_in[11];
    const float* ln2_g   = (const float*)d_in[12];
    const float* ln2_b   = (const float*)d_in[13];
    const float* fc1_w   = (const float*)d_in[14];
    const float* fc1_b   = (const float*)d_in[15];
    const float* fc2_w   = (const float*)d_in[16];
    const float* fc2_b   = (const float*)d_in[17];
    const float* rec_w   = (const float*)d_in[18];
    const float* rec_b   = (const float*)d_in[19];
    float* out = (float*)d_out;
    char* wsb = (char*)d_ws;

    float*          e        = (float*)wsb;
    unsigned short* bias_il  = (unsigned short*)(wsb + 50331648);
    unsigned short* wt       = (unsigned short*)(wsb + 51904512);
    unsigned short* pwb      = wt + 1769472;
    unsigned short* rwt      = wt + 1794048;
    char*           stage    = wsb + 55541760;
    size_t scap = ws_size > 55541760 ? ws_size - 55541760 : 0;

    int WCH = 512;
    while (WCH > 16 && (size_t)WCH*128*1920 > scap) WCH >>= 1;

    for (int d = 0; d < 4; ++d){
        unsigned short* wl = wt + (size_t)d*442368;
        wt_convert<<<(110592+255)/256, 256, 0, stream>>>(qkv_w  + (size_t)d*110592, wl,          192, 576);
        wt_convert<<<( 36864+255)/256, 256, 0, stream>>>(proj_w + (size_t)d* 36864, wl + 110592, 192, 192);
        fc1_il_convert<<<576, 256, 0, stream>>>(fc1_w + (size_t)d*147456, wl + 147456);
        fc2_il_convert<<<576, 256, 0, stream>>>(fc2_w + (size_t)d*147456, wl + 294912);
    }
    pe_conv<<<96, 256, 0, stream>>>(pe_w, pwb, 24576);
    wt_convert<<<96, 256, 0, stream>>>(rec_w, rwt, 192, 128);

    bias_precompute<<<24, 128, 0, stream>>>(rpb, bias_il);
    patch_embed_mfma<<<1024, 256, 0, stream>>>(x, pwb, pe_b, pe_ln_g, pe_ln_b, e);

    for (int d = 0; d < 4; ++d){
        int sh = d & 1;
        unsigned short* wl = wt + (size_t)d*442368;
        for (int w0 = 0; w0 < 512; w0 += WCH){
            int rows = WCH*128;
            unsigned short* bufc = (unsigned short*)stage;
            unsigned short* qkc  = (unsigned short*)(stage + (size_t)rows*384);
            unsigned short* vc   = (unsigned short*)(stage + (size_t)rows*1152);
            unsigned short* oc   = (unsigned short*)(stage + (size_t)rows*1536);
            ln_kernel<<<rows, 192, 0, stream>>>(
                e, bufc, ln1_g + d*CCH, ln1_b + d*CCH, sh, w0*128);
            gemm_mfma<5><<<dim3(9, rows/128), 256, 0, stream>>>(
                bufc, wl, qkv_b + d*3*CCH, qkc, vc, 576, 192, 0, 0);
            attn_mfma<<<WCH*HEADS, 256, 0, stream>>>(
                qkc, vc, oc, bias_il + (size_t)d*HEADS*16384, sh, w0);
            gemm_mfma<2><<<dim3(3, rows/128), 256, 0, stream>>>(
                oc, wl + 110592, proj_b + d*CCH, e, nullptr, 192, 192, sh, w0*128);
        }
        mlp_fused<<<1024, 256, 0, stream>>>(
            e, wl + 147456, fc1_b + d*4*CCH, wl + 294912, fc2_b + d*CCH,
            ln2_g + d*CCH, ln2_b + d*CCH);
    }
    recon_mfma<<<1024, 256, 0, stream>>>(e, rwt, rec_b, out);
}

// Round 7
// 1476.755 us; speedup vs baseline: 1.4028x; 1.4028x over previous
//
#include <hip/hip_runtime.h>
#include <math.h>

// SwinDecoder on MI355X. Round 14: identical to R13 (bench infra failed
// before producing a measurement; source re-audited for faults - none).
// MLP as two high-occupancy GEMM passes.
// R7-R12 post-mortems: the fused mlp (24-48KB wave-private LDS) caps
// residency at ~2 blocks/CU; every scheduling/conflict/VALU fix failed
// because per-phase latency had nothing to hide under. Meanwhile
// gemm_mfma<5> (same 2-barrier structure, 12KB LDS, ~8 blocks/CU) runs
// fast on comparable FLOPs. So: ln2 (ln_kernel, no gather) -> gemm<6>
// (fc1 + gelu epilogue -> h bf16) -> gemm<7> (fc2 + residual into e).
// h/a live in the attention stage region (dead at mlp time; 1920 B/row).
// Attention path unchanged from R6/R7. Weights in R9 wt layout.
// ws layout (bytes):
//   e        : 0          .. 50,331,648   fp32 [65536][192]
//   bias_il  : 50,331,648 .. 51,118,080   bf16 interleaved [4][6][16384]
//   wt       : 51,904,512 .. 55,541,760   bf16 weights (4 layers + pe + rec)
//   stage    : 55,541,760 .. attn: bufc|qkc|vc|oc ; mlp: a(384B/row)|h(1536B/row)

#define CCH 192
#define HEADS 6

typedef __attribute__((ext_vector_type(8))) short bf16x8;
typedef __attribute__((ext_vector_type(4))) float f32x4;

__device__ __forceinline__ unsigned short f2bf(float f){
    union { float f; unsigned int u; } x; x.f = f;
    unsigned int r = (x.u + 0x7fffu + ((x.u >> 16) & 1u)) >> 16;
    return (unsigned short)r;
}
__device__ __forceinline__ float bf2f(unsigned short h){
    union { unsigned int u; float f; } x; x.u = ((unsigned int)h)<<16;
    return x.f;
}

__device__ __forceinline__ void async16(const void* g, void* l){
    __builtin_amdgcn_global_load_lds(
        (const __attribute__((address_space(1))) void*)g,
        (__attribute__((address_space(3))) void*)l, 16, 0, 0);
}

__device__ __forceinline__ ushort4 cvt4(float4 v){
    ushort4 r; r.x=f2bf(v.x); r.y=f2bf(v.y); r.z=f2bf(v.z); r.w=f2bf(v.w);
    return r;
}

__device__ __forceinline__ int zone_z(int z){ return z<30?0:(z<31?1:2); }
__device__ __forceinline__ int zone_hw(int h){ return h<24?0:(h<28?1:2); }

// gelu with A&S 7.1.26 erf: |err| <= 1.5e-7, branchless, 1 v_exp + 1 v_rcp.
__device__ __forceinline__ float gelu_f(float v){
    float xx = v*0.70710678118654752f;
    float ax = fabsf(xx);
    float ti = __builtin_amdgcn_rcpf(fmaf(0.3275911f, ax, 1.f));
    float p  = fmaf(ti, 1.061405429f, -1.453152027f);
    p = fmaf(ti, p, 1.421413741f);
    p = fmaf(ti, p, -0.284496736f);
    p = fmaf(ti, p, 0.254829592f);
    p = p * ti;
    float ex = __expf(-ax*ax);
    float er = fmaf(-p, ex, 1.f);
    er = __builtin_copysignf(er, xx);
    return 0.5f*v*(1.f + er);
}

// ---------------- weight convert+transpose: w[K][N] fp32 -> wt[N][K] bf16 --
__global__ void wt_convert(const float* __restrict__ w, unsigned short* __restrict__ wt,
                           int K, int N)
{
    int idx = blockIdx.x*256 + threadIdx.x;
    if (idx >= K*N) return;
    int n = idx / K, k = idx - n*K;
    wt[idx] = f2bf(w[(size_t)k*N + n]);
}

// ---------------- plain fp32 -> bf16 convert -------------------------------
__global__ void pe_conv(const float* __restrict__ w, unsigned short* __restrict__ o, int n)
{
    int i = blockIdx.x*256 + threadIdx.x;
    if (i < n) o[i] = f2bf(w[i]);
}

// ---- rel-pos bias -> bf16 in MFMA-interleaved layout ----------------------
__global__ void bias_precompute(const float* __restrict__ rpb,
                                unsigned short* __restrict__ bias_il)
{
    int d = blockIdx.x / HEADS, head = blockIdx.x % HEADS;
    int n = threadIdx.x;
    int i1 = n>>6, j1 = (n>>3)&7, k1 = n&7;
    const float* rp = rpb + d*675*HEADS;
    unsigned short* out = bias_il + (size_t)blockIdx.x*16384;
    int rbase = (n>>4)*2048 + (n&15)*8;
    for (int m = 0; m < 128; ++m){
        int i2 = m>>6, j2 = (m>>3)&7, k2 = m&7;
        int idx = (i1-i2+1)*225 + (j1-j2+7)*15 + (k1-k2+7);
        int off = rbase + (m>>5)*512 + ((m>>3)&3)*128 + (m&7);
        out[off] = f2bf(rp[idx*HEADS + head]);
    }
}

// ---------------- patch embed via MFMA, LN fused in epilogue ---------------
__global__ __launch_bounds__(256) void patch_embed_mfma(
    const float* __restrict__ x, const unsigned short* __restrict__ pwb,
    const float* __restrict__ pe_b, const float* __restrict__ gg,
    const float* __restrict__ bb, float* __restrict__ e)
{
    __shared__ __align__(16) unsigned short As[64*132];
    __shared__ __align__(16) unsigned short Bs[96*132];
    int t = threadIdx.x;
    int wave = t>>6, lane = t&63, quad = lane>>4, l16 = lane&15;
    int m0 = blockIdx.x*64;

    {
        int row = t & 63, cg = (t>>6)*8;
        int pos = m0 + row;
        int w = pos&31, h=(pos>>5)&31, z=(pos>>10)&31, b=pos>>15;
        #pragma unroll
        for (int cc=0; cc<8; ++cc){
            int chunk = cg + cc;
            int c = chunk>>3, i=(chunk>>2)&1, j=chunk&3;
            float4 v = *(const float4*)&x[ (((size_t)(b*4+c)*64 + (z*2+i))*128 + (h*4+j))*128 + w*4 ];
            *(ushort4*)&As[row*132 + chunk*4] = cvt4(v);
        }
    }

    f32x4 acc[12] = {};
    #pragma unroll
    for (int ph = 0; ph < 2; ++ph){
        if (ph) __syncthreads();
        #pragma unroll
        for (int it=0; it<6; ++it){
            int g = it*256 + t;
            int row = g >> 4, c8 = g & 15;
            const unsigned short* src = pwb + ((size_t)(ph*96+row))*128 + c8*8;
            uint4 u = *(const uint4*)src;
            unsigned short* dst = &Bs[row*132 + c8*8];
            *(uint2*)dst       = make_uint2(u.x, u.y);
            *(uint2*)(dst+4)   = make_uint2(u.z, u.w);
        }
        __syncthreads();
        #pragma unroll
        for (int ks=0; ks<4; ++ks){
            bf16x8 af = *(const bf16x8*)&As[(wave*16 + l16)*132 + ks*32 + quad*8];
            #pragma unroll
            for (int nt=0; nt<6; ++nt){
                bf16x8 bf = *(const bf16x8*)&Bs[(nt*16 + l16)*132 + ks*32 + quad*8];
                acc[ph*6+nt] = __builtin_amdgcn_mfma_f32_16x16x32_bf16(
                    af, bf, acc[ph*6+nt], 0, 0, 0);
            }
        }
    }

    float pb[12], gv[12], bv[12];
    #pragma unroll
    for (int nt=0; nt<12; ++nt){
        int col = nt*16 + l16;
        pb[nt] = pe_b[col]; gv[nt] = gg[col]; bv[nt] = bb[col];
    }
    #pragma unroll
    for (int r=0; r<4; ++r){
        int row = wave*16 + quad*4 + r;
        int pos = m0 + row;
        float sv[12], s1 = 0.f, s2 = 0.f;
        #pragma unroll
        for (int nt=0; nt<12; ++nt){
            float v = acc[nt][r] + pb[nt];
            sv[nt] = v; s1 += v; s2 += v*v;
        }
        #pragma unroll
        for (int off=1; off<16; off<<=1){
            s1 += __shfl_xor(s1, off); s2 += __shfl_xor(s2, off);
        }
        float mean = s1*(1.f/192.f);
        float rstd = rsqrtf(s2*(1.f/192.f) - mean*mean + 1e-5f);
        #pragma unroll
        for (int nt=0; nt<12; ++nt){
            int col = nt*16 + l16;
            e[(size_t)pos*CCH + col] = (sv[nt]-mean)*rstd*gv[nt] + bv[nt];
        }
    }
}

// ---------------- reconstruction via MFMA ----------------------------------
__global__ __launch_bounds__(256) void recon_mfma(
    const float* __restrict__ e, const unsigned short* __restrict__ rwt,
    const float* __restrict__ rec_b, float* __restrict__ out)
{
    __shared__ __align__(16) unsigned short As[64*196];
    __shared__ __align__(16) unsigned short Bs[64*196];
    int t = threadIdx.x;
    int wave = t>>6, lane = t&63, quad = lane>>4, l16 = lane&15;
    int m0 = blockIdx.x*64;

    #pragma unroll
    for (int it=0; it<12; ++it){
        int g = it*256 + t;
        int row = g/48, c4 = g - row*48;
        float4 v = *(const float4*)&e[(size_t)(m0+row)*CCH + c4*4];
        *(ushort4*)&As[row*196 + c4*4] = cvt4(v);
    }

    f32x4 acc[8] = {};
    #pragma unroll
    for (int ph = 0; ph < 2; ++ph){
        if (ph) __syncthreads();
        #pragma unroll
        for (int it=0; it<6; ++it){
            int g = it*256 + t;
            int row = g/24, c8 = g - row*24;
            const unsigned short* src = rwt + ((size_t)(ph*64+row))*192 + c8*8;
            uint4 u = *(const uint4*)src;
            unsigned short* dst = &Bs[row*196 + c8*8];
            *(uint2*)dst     = make_uint2(u.x, u.y);
            *(uint2*)(dst+4) = make_uint2(u.z, u.w);
        }
        __syncthreads();
        #pragma unroll
        for (int ks=0; ks<6; ++ks){
            bf16x8 af = *(const bf16x8*)&As[(wave*16 + l16)*196 + ks*32 + quad*8];
            #pragma unroll
            for (int nt=0; nt<4; ++nt){
                bf16x8 bf = *(const bf16x8*)&Bs[(nt*16 + l16)*196 + ks*32 + quad*8];
                acc[ph*4+nt] = __builtin_amdgcn_mfma_f32_16x16x32_bf16(
                    af, bf, acc[ph*4+nt], 0, 0, 0);
            }
        }
    }

    #pragma unroll
    for (int nt=0; nt<8; ++nt){
        int col = nt*16 + l16;
        int o = col>>5, i = (col>>4)&1, j = (col>>2)&3, k = col&3;
        float rb = rec_b[o];
        #pragma unroll
        for (int r=0; r<4; ++r){
            int pos = m0 + wave*16 + quad*4 + r;
            int w = pos&31, h=(pos>>5)&31, z=(pos>>10)&31, b=pos>>15;
            out[ (((size_t)(b*4+o)*64 + (z*2+i))*128 + (h*4+j))*128 + (w*4+k) ]
                = acc[nt][r] + rb;
        }
    }
}

// ------- LayerNorm -> bf16; gather=1: window gather (ln1); 0: plain (ln2) --
__global__ __launch_bounds__(192) void ln_kernel(
    const float* __restrict__ in, unsigned short* __restrict__ outp,
    const float* __restrict__ gg, const float* __restrict__ bb,
    int shifted, int row0, int gather)
{
    int tid = threadIdx.x;
    int r = blockIdx.x + row0;
    int src;
    if (gather){
        int wb = r>>7, tok = r&127;
        int b = wb>>8, nw = wb&255;
        int zs = (nw>>4)*2 + (tok>>6);
        int hs = ((nw>>2)&3)*8 + ((tok>>3)&7);
        int ws = (nw&3)*8 + (tok&7);
        int z,h,w;
        if (shifted){ z=(zs+1)&31; h=(hs+4)&31; w=(ws+4)&31; }
        else        { z=zs; h=hs; w=ws; }
        src = ((b*32+z)*32+h)*32+w;
    } else {
        src = r;
    }
    float val = in[(size_t)src*CCH + tid];
    float s = val, s2 = val*val;
    for (int off=32; off>=1; off>>=1){ s += __shfl_xor(s,off); s2 += __shfl_xor(s2,off); }
    __shared__ float red[2][3];
    if ((tid&63)==0){ red[0][tid>>6]=s; red[1][tid>>6]=s2; }
    __syncthreads();
    float sum = red[0][0]+red[0][1]+red[0][2];
    float sq  = red[1][0]+red[1][1]+red[1][2];
    float mean = sum*(1.f/192.f);
    float rstd = rsqrtf(sq*(1.f/192.f) - mean*mean + 1e-5f);
    outp[(size_t)blockIdx.x*CCH + tid] = f2bf((val-mean)*rstd*gg[tid] + bb[tid]);
}

// ---------------- bf16 MFMA GEMM ------------------------------------------
// MODE 2: window-reverse residual add (fp32 e).
// MODE 5: qkv split: n<384 -> Ch[m][384] (Q|K); n>=384 -> Vout[win][d][tok].
// MODE 6: fc1: gelu(v) -> bf16 h[m][768].
// MODE 7: fc2: e[(m+row0)][n] += v (plain rows, no window mapping).
template<int MODE>
__global__ __launch_bounds__(256) void gemm_mfma(
    const unsigned short* __restrict__ A, const unsigned short* __restrict__ Bt,
    const float* __restrict__ bias, void* __restrict__ Cout,
    unsigned short* __restrict__ Vout,
    int N, int K, int shifted, int row0)
{
    __shared__ __align__(16) unsigned short As[128*32];
    __shared__ __align__(16) unsigned short Bs[64*32];
    int t = threadIdx.x;
    int wave = t >> 6, lane = t & 63;
    int quad = lane >> 4, l16 = lane & 15;
    int m0 = blockIdx.y * 128, n0 = blockIdx.x * 64;

    f32x4 acc[2][4] = {};
    int ldrow = lane >> 2;
    int ldk   = (lane & 3) * 8;

    for (int k0 = 0; k0 < K; k0 += 32){
        #pragma unroll
        for (int s2 = 0; s2 < 2; ++s2){
            int s = wave*2 + s2;
            async16(A + (size_t)(m0 + s*16 + ldrow)*K + k0 + ldk, &As[s*512]);
        }
        async16(Bt + (size_t)(n0 + wave*16 + ldrow)*K + k0 + ldk, &Bs[wave*512]);
        __syncthreads();
        bf16x8 af[2], bfr[4];
        #pragma unroll
        for (int mt=0; mt<2; ++mt)
            af[mt] = *(const bf16x8*)&As[(wave*32 + mt*16 + l16)*32 + quad*8];
        #pragma unroll
        for (int nt=0; nt<4; ++nt)
            bfr[nt] = *(const bf16x8*)&Bs[(nt*16 + l16)*32 + quad*8];
        #pragma unroll
        for (int mt=0; mt<2; ++mt)
            #pragma unroll
            for (int nt=0; nt<4; ++nt)
                acc[mt][nt] = __builtin_amdgcn_mfma_f32_16x16x32_bf16(
                    af[mt], bfr[nt], acc[mt][nt], 0, 0, 0);
        __syncthreads();
    }

    float* Cf = (float*)Cout;
    unsigned short* Ch = (unsigned short*)Cout;
    #pragma unroll
    for (int mt=0; mt<2; ++mt){
        #pragma unroll
        for (int nt=0; nt<4; ++nt){
            int n = n0 + nt*16 + l16;
            if (MODE==5 && n0 + nt*16 >= 384){
                int d = n - 384;
                int win = m0 >> 7;
                int tok0 = wave*32 + mt*16 + quad*4;
                float bn = bias[n];
                ushort4 vv;
                vv.x = f2bf(acc[mt][nt][0]+bn); vv.y = f2bf(acc[mt][nt][1]+bn);
                vv.z = f2bf(acc[mt][nt][2]+bn); vv.w = f2bf(acc[mt][nt][3]+bn);
                *(ushort4*)&Vout[((size_t)win*192 + d)*128 + tok0] = vv;
                continue;
            }
            #pragma unroll
            for (int r=0; r<4; ++r){
                int m = m0 + wave*32 + mt*16 + quad*4 + r;
                float v = acc[mt][nt][r] + bias[n];
                if (MODE==5){
                    Ch[(size_t)m*384 + n] = f2bf(v);
                } else if (MODE==6){
                    Ch[(size_t)m*768 + n] = f2bf(gelu_f(v));
                } else if (MODE==7){
                    Cf[(size_t)(m + row0)*CCH + n] += v;
                } else {
                    int mg = m + row0;
                    int wb = mg>>7, tok = mg&127;
                    int b = wb>>8, nw = wb&255;
                    int zs = (nw>>4)*2 + (tok>>6);
                    int hs = ((nw>>2)&3)*8 + ((tok>>3)&7);
                    int ws = (nw&3)*8 + (tok&7);
                    int z,h,w;
                    if (shifted){ z=(zs+1)&31; h=(hs+4)&31; w=(ws+4)&31; }
                    else        { z=zs; h=hs; w=ws; }
                    Cf[(size_t)(((b*32+z)*32+h)*32+w)*CCH + n] += v;
                }
            }
        }
    }
}

// ---------------- MFMA attention (unchanged from R6) -----------------------
__global__ __launch_bounds__(256) void attn_mfma(
    const unsigned short* __restrict__ qk,
    const unsigned short* __restrict__ vbuf,
    unsigned short* __restrict__ obuf,
    const unsigned short* __restrict__ bias_layer,
    int shifted, int wb0)
{
    __shared__ __align__(16) unsigned short Ks[4096];
    __shared__ __align__(16) unsigned short Vt[4096];
    __shared__ __align__(16) unsigned short Ps[16384];
    __shared__ float linv[128];
    __shared__ int grp[128];

    int t = threadIdx.x;
    int wave = t >> 6, lane = t & 63;
    int quad = lane >> 4, l16 = lane & 15;
    int wb = blockIdx.x / HEADS;
    int head = blockIdx.x % HEADS;
    int nw = (wb + wb0) & 255;

    const unsigned short* qkw = qk + (size_t)wb*128*384;

    bf16x8 af[2];
    #pragma unroll
    for (int mt=0; mt<2; ++mt)
        af[mt] = *(const bf16x8*)(qkw + (size_t)(wave*32 + mt*16 + l16)*384 + head*32 + quad*8);

    {
        int chunk = lane >> 4, low = lane & 15;
        #pragma unroll
        for (int i=0; i<2; ++i){
            int j = wave*2 + i;
            async16(qkw + (size_t)(j*16 + low)*384 + 192 + head*32 + chunk*8, &Ks[j*512]);
        }
        const unsigned short* vb = vbuf + ((size_t)wb*192 + head*32)*128;
        #pragma unroll
        for (int i=0; i<2; ++i){
            int j = wave*2 + i; int dgrp = j>>2, tg = j&3;
            async16(vb + (size_t)(dgrp*16 + low)*128 + tg*32 + chunk*8, &Vt[j*512]);
        }
        const unsigned short* bsrc = bias_layer + (size_t)head*16384;
        #pragma unroll
        for (int i=0; i<8; ++i){
            int j = wave*8 + i;
            async16(bsrc + j*512 + lane*8, &Ps[j*512]);
        }
    }
    if (t < 128 && shifted){
        int zs = (nw>>4)*2 + (t>>6);
        int hs = ((nw>>2)&3)*8 + ((t>>3)&7);
        int ws = (nw&3)*8 + (t&7);
        grp[t] = zone_z(zs)*9 + zone_hw(hs)*3 + zone_hw(ws);
    }
    __syncthreads();

    f32x4 sacc[2][8] = {};
    #pragma unroll
    for (int nt=0; nt<8; ++nt){
        bf16x8 bfr = *(const bf16x8*)&Ks[nt*512 + quad*128 + l16*8];
        sacc[0][nt] = __builtin_amdgcn_mfma_f32_16x16x32_bf16(af[0], bfr, sacc[0][nt], 0,0,0);
        sacc[1][nt] = __builtin_amdgcn_mfma_f32_16x16x32_bf16(af[1], bfr, sacc[1][nt], 0,0,0);
    }

    const float scale = 0.17677669529663689f;
    #pragma unroll
    for (int mt=0; mt<2; ++mt){
        #pragma unroll
        for (int r=0; r<4; ++r){
            int row = wave*32 + mt*16 + quad*4 + r;
            int rbase = (wave*2+mt)*2048 + (quad*4+r)*8;
            int myg = shifted ? grp[row] : 0;
            float sv[8]; int offv[8];
            float mloc = -1e30f;
            #pragma unroll
            for (int nt=0; nt<8; ++nt){
                int off = rbase + (nt>>1)*512 + (((nt&1)<<1) + (l16>>3))*128 + (l16&7);
                offv[nt] = off;
                float s = sacc[mt][nt][r]*scale + bf2f(Ps[off]);
                if (shifted && grp[nt*16+l16] != myg) s -= 100.f;
                sv[nt] = s;
                mloc = fmaxf(mloc, s);
            }
            #pragma unroll
            for (int off=1; off<16; off<<=1) mloc = fmaxf(mloc, __shfl_xor(mloc, off));
            float lloc = 0.f;
            #pragma unroll
            for (int nt=0; nt<8; ++nt){
                float p = __expf(sv[nt]-mloc);
                sv[nt] = p; lloc += p;
            }
            #pragma unroll
            for (int off=1; off<16; off<<=1) lloc += __shfl_xor(lloc, off);
            #pragma unroll
            for (int nt=0; nt<8; ++nt)
                Ps[offv[nt]] = f2bf(sv[nt]);
            if (l16==0) linv[row] = 1.f/lloc;
        }
    }

    f32x4 oacc[2][2] = {};
    #pragma unroll
    for (int ks=0; ks<4; ++ks){
        bf16x8 av0 = *(const bf16x8*)&Vt[         ks*512 + quad*128 + l16*8];
        bf16x8 av1 = *(const bf16x8*)&Vt[ 2048 +  ks*512 + quad*128 + l16*8];
        bf16x8 pf0 = *(const bf16x8*)&Ps[(wave*2+0)*2048 + ks*512 + quad*128 + l16*8];
        bf16x8 pf1 = *(const bf16x8*)&Ps[(wave*2+1)*2048 + ks*512 + quad*128 + l16*8];
        oacc[0][0] = __builtin_amdgcn_mfma_f32_16x16x32_bf16(av0, pf0, oacc[0][0], 0,0,0);
        oacc[0][1] = __builtin_amdgcn_mfma_f32_16x16x32_bf16(av1, pf0, oacc[0][1], 0,0,0);
        oacc[1][0] = __builtin_amdgcn_mfma_f32_16x16x32_bf16(av0, pf1, oacc[1][0], 0,0,0);
        oacc[1][1] = __builtin_amdgcn_mfma_f32_16x16x32_bf16(av1, pf1, oacc[1][1], 0,0,0);
    }

    #pragma unroll
    for (int mt=0; mt<2; ++mt){
        int token = wave*32 + mt*16 + l16;
        float inv = linv[token];
        unsigned short* dst = obuf + (size_t)(wb*128+token)*CCH + head*32;
        #pragma unroll
        for (int dt=0; dt<2; ++dt){
            ushort4 v4;
            v4.x = f2bf(oacc[mt][dt][0]*inv);
            v4.y = f2bf(oacc[mt][dt][1]*inv);
            v4.z = f2bf(oacc[mt][dt][2]*inv);
            v4.w = f2bf(oacc[mt][dt][3]*inv);
            *(ushort4*)&dst[dt*16 + quad*4] = v4;
        }
    }
}

extern "C" void kernel_launch(void* const* d_in, const int* in_sizes, int n_in,
                              void* d_out, int out_size, void* d_ws, size_t ws_size,
                              hipStream_t stream) {
    const float* x       = (const float*)d_in[0];
    const float* pe_w    = (const float*)d_in[1];
    const float* pe_b    = (const float*)d_in[2];
    const float* pe_ln_g = (const float*)d_in[3];
    const float* pe_ln_b = (const float*)d_in[4];
    const float* ln1_g   = (const float*)d_in[5];
    const float* ln1_b   = (const float*)d_in[6];
    const float* qkv_w   = (const float*)d_in[7];
    const float* qkv_b   = (const float*)d_in[8];
    const float* proj_w  = (const float*)d_in[9];
    const float* proj_b  = (const float*)d_in[10];
    const float* rpb     = (const float*)d_in[11];
    const float* ln2_g   = (const float*)d_in[12];
    const float* ln2_b   = (const float*)d_in[13];
    const float* fc1_w   = (const float*)d_in[14];
    const float* fc1_b   = (const float*)d_in[15];
    const float* fc2_w   = (const float*)d_in[16];
    const float* fc2_b   = (const float*)d_in[17];
    const float* rec_w   = (const float*)d_in[18];
    const float* rec_b   = (const float*)d_in[19];
    float* out = (float*)d_out;
    char* wsb = (char*)d_ws;

    float*          e        = (float*)wsb;
    unsigned short* bias_il  = (unsigned short*)(wsb + 50331648);
    unsigned short* wt       = (unsigned short*)(wsb + 51904512);
    unsigned short* pwb      = wt + 1769472;
    unsigned short* rwt      = wt + 1794048;
    char*           stage    = wsb + 55541760;
    size_t scap = ws_size > 55541760 ? ws_size - 55541760 : 0;

    int WCH = 512;
    while (WCH > 16 && (size_t)WCH*128*1920 > scap) WCH >>= 1;

    for (int d = 0; d < 4; ++d){
        unsigned short* wl = wt + (size_t)d*442368;
        wt_convert<<<(110592+255)/256, 256, 0, stream>>>(qkv_w  + (size_t)d*110592, wl,          192, 576);
        wt_convert<<<( 36864+255)/256, 256, 0, stream>>>(proj_w + (size_t)d* 36864, wl + 110592, 192, 192);
        wt_convert<<<(147456+255)/256, 256, 0, stream>>>(fc1_w  + (size_t)d*147456, wl + 147456, 192, 768);
        wt_convert<<<(147456+255)/256, 256, 0, stream>>>(fc2_w  + (size_t)d*147456, wl + 294912, 768, 192);
    }
    pe_conv<<<96, 256, 0, stream>>>(pe_w, pwb, 24576);
    wt_convert<<<96, 256, 0, stream>>>(rec_w, rwt, 192, 128);

    bias_precompute<<<24, 128, 0, stream>>>(rpb, bias_il);
    patch_embed_mfma<<<1024, 256, 0, stream>>>(x, pwb, pe_b, pe_ln_g, pe_ln_b, e);

    for (int d = 0; d < 4; ++d){
        int sh = d & 1;
        unsigned short* wl = wt + (size_t)d*442368;
        for (int w0 = 0; w0 < 512; w0 += WCH){
            int rows = WCH*128;
            unsigned short* bufc = (unsigned short*)stage;
            unsigned short* qkc  = (unsigned short*)(stage + (size_t)rows*384);
            unsigned short* vc   = (unsigned short*)(stage + (size_t)rows*1152);
            unsigned short* oc   = (unsigned short*)(stage + (size_t)rows*1536);
            ln_kernel<<<rows, 192, 0, stream>>>(
                e, bufc, ln1_g + d*CCH, ln1_b + d*CCH, sh, w0*128, 1);
            gemm_mfma<5><<<dim3(9, rows/128), 256, 0, stream>>>(
                bufc, wl, qkv_b + d*3*CCH, qkc, vc, 576, 192, 0, 0);
            attn_mfma<<<WCH*HEADS, 256, 0, stream>>>(
                qkc, vc, oc, bias_il + (size_t)d*HEADS*16384, sh, w0);
            gemm_mfma<2><<<dim3(3, rows/128), 256, 0, stream>>>(
                oc, wl + 110592, proj_b + d*CCH, e, nullptr, 192, 192, sh, w0*128);
        }
        // ---- MLP: ln2 -> fc1+gelu(h bf16) -> fc2+residual, high-occupancy ----
        for (int r0 = 0; r0 < 65536; r0 += WCH*128){
            int rows = WCH*128;
            unsigned short* abuf = (unsigned short*)stage;
            unsigned short* hbuf = (unsigned short*)(stage + (size_t)rows*384);
            ln_kernel<<<rows, 192, 0, stream>>>(
                e, abuf, ln2_g + d*CCH, ln2_b + d*CCH, 0, r0, 0);
            gemm_mfma<6><<<dim3(12, rows/128), 256, 0, stream>>>(
                abuf, wl + 147456, fc1_b + d*4*CCH, hbuf, nullptr, 768, 192, 0, 0);
            gemm_mfma<7><<<dim3(3, rows/128), 256, 0, stream>>>(
                hbuf, wl + 294912, fc2_b + d*CCH, e, nullptr, 192, 768, 0, r0);
        }
    }
    recon_mfma<<<1024, 256, 0, stream>>>(e, rwt, rec_b, out);
}

// Round 8
// 1383.008 us; speedup vs baseline: 1.4979x; 1.0678x over previous
//
#include <hip/hip_runtime.h>
#include <math.h>

// SwinDecoder on MI355X. Round 15: widen N-tiles in the MLP GEMMs.
// R13/14 result: split MLP == fused MLP (~160-166us/layer); top-5 is now
// gemm<6> (fc1): 67.5us, FETCH 98.8MB (=4x A size: 12 n-blocks re-read the
// 25MB A, h write-stream evicts it from L3), WRITE 98.5MB (=h), MfmaUtil
// 12%, VALUBusy 65%. Fix: template param NT (n-tiles/block):
//   gemm<6>: NT=8  (grid 6x512)  - A re-reads halved, 16 MFMA/k-step
//   gemm<7>: NT=12 (grid 1x512)  - h read once (was 3x), 24 MFMA/k-step
// Attention-path GEMMs (NT=4) untouched for attribution.
// ws layout (bytes):
//   e        : 0          .. 50,331,648   fp32 [65536][192]
//   bias_il  : 50,331,648 .. 51,118,080   bf16 interleaved [4][6][16384]
//   wt       : 51,904,512 .. 55,541,760   bf16 weights (4 layers + pe + rec)
//   stage    : 55,541,760 .. attn: bufc|qkc|vc|oc ; mlp: a(384B/row)|h(1536B/row)

#define CCH 192
#define HEADS 6

typedef __attribute__((ext_vector_type(8))) short bf16x8;
typedef __attribute__((ext_vector_type(4))) float f32x4;

__device__ __forceinline__ unsigned short f2bf(float f){
    union { float f; unsigned int u; } x; x.f = f;
    unsigned int r = (x.u + 0x7fffu + ((x.u >> 16) & 1u)) >> 16;
    return (unsigned short)r;
}
__device__ __forceinline__ float bf2f(unsigned short h){
    union { unsigned int u; float f; } x; x.u = ((unsigned int)h)<<16;
    return x.f;
}

__device__ __forceinline__ void async16(const void* g, void* l){
    __builtin_amdgcn_global_load_lds(
        (const __attribute__((address_space(1))) void*)g,
        (__attribute__((address_space(3))) void*)l, 16, 0, 0);
}

__device__ __forceinline__ ushort4 cvt4(float4 v){
    ushort4 r; r.x=f2bf(v.x); r.y=f2bf(v.y); r.z=f2bf(v.z); r.w=f2bf(v.w);
    return r;
}

__device__ __forceinline__ int zone_z(int z){ return z<30?0:(z<31?1:2); }
__device__ __forceinline__ int zone_hw(int h){ return h<24?0:(h<28?1:2); }

// gelu with A&S 7.1.26 erf: |err| <= 1.5e-7, branchless, 1 v_exp + 1 v_rcp.
__device__ __forceinline__ float gelu_f(float v){
    float xx = v*0.70710678118654752f;
    float ax = fabsf(xx);
    float ti = __builtin_amdgcn_rcpf(fmaf(0.3275911f, ax, 1.f));
    float p  = fmaf(ti, 1.061405429f, -1.453152027f);
    p = fmaf(ti, p, 1.421413741f);
    p = fmaf(ti, p, -0.284496736f);
    p = fmaf(ti, p, 0.254829592f);
    p = p * ti;
    float ex = __expf(-ax*ax);
    float er = fmaf(-p, ex, 1.f);
    er = __builtin_copysignf(er, xx);
    return 0.5f*v*(1.f + er);
}

// ---------------- weight convert+transpose: w[K][N] fp32 -> wt[N][K] bf16 --
__global__ void wt_convert(const float* __restrict__ w, unsigned short* __restrict__ wt,
                           int K, int N)
{
    int idx = blockIdx.x*256 + threadIdx.x;
    if (idx >= K*N) return;
    int n = idx / K, k = idx - n*K;
    wt[idx] = f2bf(w[(size_t)k*N + n]);
}

// ---------------- plain fp32 -> bf16 convert -------------------------------
__global__ void pe_conv(const float* __restrict__ w, unsigned short* __restrict__ o, int n)
{
    int i = blockIdx.x*256 + threadIdx.x;
    if (i < n) o[i] = f2bf(w[i]);
}

// ---- rel-pos bias -> bf16 in MFMA-interleaved layout ----------------------
__global__ void bias_precompute(const float* __restrict__ rpb,
                                unsigned short* __restrict__ bias_il)
{
    int d = blockIdx.x / HEADS, head = blockIdx.x % HEADS;
    int n = threadIdx.x;
    int i1 = n>>6, j1 = (n>>3)&7, k1 = n&7;
    const float* rp = rpb + d*675*HEADS;
    unsigned short* out = bias_il + (size_t)blockIdx.x*16384;
    int rbase = (n>>4)*2048 + (n&15)*8;
    for (int m = 0; m < 128; ++m){
        int i2 = m>>6, j2 = (m>>3)&7, k2 = m&7;
        int idx = (i1-i2+1)*225 + (j1-j2+7)*15 + (k1-k2+7);
        int off = rbase + (m>>5)*512 + ((m>>3)&3)*128 + (m&7);
        out[off] = f2bf(rp[idx*HEADS + head]);
    }
}

// ---------------- patch embed via MFMA, LN fused in epilogue ---------------
__global__ __launch_bounds__(256) void patch_embed_mfma(
    const float* __restrict__ x, const unsigned short* __restrict__ pwb,
    const float* __restrict__ pe_b, const float* __restrict__ gg,
    const float* __restrict__ bb, float* __restrict__ e)
{
    __shared__ __align__(16) unsigned short As[64*132];
    __shared__ __align__(16) unsigned short Bs[96*132];
    int t = threadIdx.x;
    int wave = t>>6, lane = t&63, quad = lane>>4, l16 = lane&15;
    int m0 = blockIdx.x*64;

    {
        int row = t & 63, cg = (t>>6)*8;
        int pos = m0 + row;
        int w = pos&31, h=(pos>>5)&31, z=(pos>>10)&31, b=pos>>15;
        #pragma unroll
        for (int cc=0; cc<8; ++cc){
            int chunk = cg + cc;
            int c = chunk>>3, i=(chunk>>2)&1, j=chunk&3;
            float4 v = *(const float4*)&x[ (((size_t)(b*4+c)*64 + (z*2+i))*128 + (h*4+j))*128 + w*4 ];
            *(ushort4*)&As[row*132 + chunk*4] = cvt4(v);
        }
    }

    f32x4 acc[12] = {};
    #pragma unroll
    for (int ph = 0; ph < 2; ++ph){
        if (ph) __syncthreads();
        #pragma unroll
        for (int it=0; it<6; ++it){
            int g = it*256 + t;
            int row = g >> 4, c8 = g & 15;
            const unsigned short* src = pwb + ((size_t)(ph*96+row))*128 + c8*8;
            uint4 u = *(const uint4*)src;
            unsigned short* dst = &Bs[row*132 + c8*8];
            *(uint2*)dst       = make_uint2(u.x, u.y);
            *(uint2*)(dst+4)   = make_uint2(u.z, u.w);
        }
        __syncthreads();
        #pragma unroll
        for (int ks=0; ks<4; ++ks){
            bf16x8 af = *(const bf16x8*)&As[(wave*16 + l16)*132 + ks*32 + quad*8];
            #pragma unroll
            for (int nt=0; nt<6; ++nt){
                bf16x8 bf = *(const bf16x8*)&Bs[(nt*16 + l16)*132 + ks*32 + quad*8];
                acc[ph*6+nt] = __builtin_amdgcn_mfma_f32_16x16x32_bf16(
                    af, bf, acc[ph*6+nt], 0, 0, 0);
            }
        }
    }

    float pb[12], gv[12], bv[12];
    #pragma unroll
    for (int nt=0; nt<12; ++nt){
        int col = nt*16 + l16;
        pb[nt] = pe_b[col]; gv[nt] = gg[col]; bv[nt] = bb[col];
    }
    #pragma unroll
    for (int r=0; r<4; ++r){
        int row = wave*16 + quad*4 + r;
        int pos = m0 + row;
        float sv[12], s1 = 0.f, s2 = 0.f;
        #pragma unroll
        for (int nt=0; nt<12; ++nt){
            float v = acc[nt][r] + pb[nt];
            sv[nt] = v; s1 += v; s2 += v*v;
        }
        #pragma unroll
        for (int off=1; off<16; off<<=1){
            s1 += __shfl_xor(s1, off); s2 += __shfl_xor(s2, off);
        }
        float mean = s1*(1.f/192.f);
        float rstd = rsqrtf(s2*(1.f/192.f) - mean*mean + 1e-5f);
        #pragma unroll
        for (int nt=0; nt<12; ++nt){
            int col = nt*16 + l16;
            e[(size_t)pos*CCH + col] = (sv[nt]-mean)*rstd*gv[nt] + bv[nt];
        }
    }
}

// ---------------- reconstruction via MFMA ----------------------------------
__global__ __launch_bounds__(256) void recon_mfma(
    const float* __restrict__ e, const unsigned short* __restrict__ rwt,
    const float* __restrict__ rec_b, float* __restrict__ out)
{
    __shared__ __align__(16) unsigned short As[64*196];
    __shared__ __align__(16) unsigned short Bs[64*196];
    int t = threadIdx.x;
    int wave = t>>6, lane = t&63, quad = lane>>4, l16 = lane&15;
    int m0 = blockIdx.x*64;

    #pragma unroll
    for (int it=0; it<12; ++it){
        int g = it*256 + t;
        int row = g/48, c4 = g - row*48;
        float4 v = *(const float4*)&e[(size_t)(m0+row)*CCH + c4*4];
        *(ushort4*)&As[row*196 + c4*4] = cvt4(v);
    }

    f32x4 acc[8] = {};
    #pragma unroll
    for (int ph = 0; ph < 2; ++ph){
        if (ph) __syncthreads();
        #pragma unroll
        for (int it=0; it<6; ++it){
            int g = it*256 + t;
            int row = g/24, c8 = g - row*24;
            const unsigned short* src = rwt + ((size_t)(ph*64+row))*192 + c8*8;
            uint4 u = *(const uint4*)src;
            unsigned short* dst = &Bs[row*196 + c8*8];
            *(uint2*)dst     = make_uint2(u.x, u.y);
            *(uint2*)(dst+4) = make_uint2(u.z, u.w);
        }
        __syncthreads();
        #pragma unroll
        for (int ks=0; ks<6; ++ks){
            bf16x8 af = *(const bf16x8*)&As[(wave*16 + l16)*196 + ks*32 + quad*8];
            #pragma unroll
            for (int nt=0; nt<4; ++nt){
                bf16x8 bf = *(const bf16x8*)&Bs[(nt*16 + l16)*196 + ks*32 + quad*8];
                acc[ph*4+nt] = __builtin_amdgcn_mfma_f32_16x16x32_bf16(
                    af, bf, acc[ph*4+nt], 0, 0, 0);
            }
        }
    }

    #pragma unroll
    for (int nt=0; nt<8; ++nt){
        int col = nt*16 + l16;
        int o = col>>5, i = (col>>4)&1, j = (col>>2)&3, k = col&3;
        float rb = rec_b[o];
        #pragma unroll
        for (int r=0; r<4; ++r){
            int pos = m0 + wave*16 + quad*4 + r;
            int w = pos&31, h=(pos>>5)&31, z=(pos>>10)&31, b=pos>>15;
            out[ (((size_t)(b*4+o)*64 + (z*2+i))*128 + (h*4+j))*128 + (w*4+k) ]
                = acc[nt][r] + rb;
        }
    }
}

// ------- LayerNorm -> bf16; gather=1: window gather (ln1); 0: plain (ln2) --
__global__ __launch_bounds__(192) void ln_kernel(
    const float* __restrict__ in, unsigned short* __restrict__ outp,
    const float* __restrict__ gg, const float* __restrict__ bb,
    int shifted, int row0, int gather)
{
    int tid = threadIdx.x;
    int r = blockIdx.x + row0;
    int src;
    if (gather){
        int wb = r>>7, tok = r&127;
        int b = wb>>8, nw = wb&255;
        int zs = (nw>>4)*2 + (tok>>6);
        int hs = ((nw>>2)&3)*8 + ((tok>>3)&7);
        int ws = (nw&3)*8 + (tok&7);
        int z,h,w;
        if (shifted){ z=(zs+1)&31; h=(hs+4)&31; w=(ws+4)&31; }
        else        { z=zs; h=hs; w=ws; }
        src = ((b*32+z)*32+h)*32+w;
    } else {
        src = r;
    }
    float val = in[(size_t)src*CCH + tid];
    float s = val, s2 = val*val;
    for (int off=32; off>=1; off>>=1){ s += __shfl_xor(s,off); s2 += __shfl_xor(s2,off); }
    __shared__ float red[2][3];
    if ((tid&63)==0){ red[0][tid>>6]=s; red[1][tid>>6]=s2; }
    __syncthreads();
    float sum = red[0][0]+red[0][1]+red[0][2];
    float sq  = red[1][0]+red[1][1]+red[1][2];
    float mean = sum*(1.f/192.f);
    float rstd = rsqrtf(sq*(1.f/192.f) - mean*mean + 1e-5f);
    outp[(size_t)blockIdx.x*CCH + tid] = f2bf((val-mean)*rstd*gg[tid] + bb[tid]);
}

// ---------------- bf16 MFMA GEMM (NT = n-tiles of 16 per block) -----------
// MODE 2: window-reverse residual add (fp32 e).
// MODE 5: qkv split: n<384 -> Ch[m][384] (Q|K); n>=384 -> Vout[win][d][tok].
// MODE 6: fc1: gelu(v) -> bf16 h[m][768].
// MODE 7: fc2: e[(m+row0)][n] += v (plain rows, no window mapping).
template<int MODE, int NT>
__global__ __launch_bounds__(256) void gemm_mfma(
    const unsigned short* __restrict__ A, const unsigned short* __restrict__ Bt,
    const float* __restrict__ bias, void* __restrict__ Cout,
    unsigned short* __restrict__ Vout,
    int N, int K, int shifted, int row0)
{
    __shared__ __align__(16) unsigned short As[128*32];
    __shared__ __align__(16) unsigned short Bs[NT*16*32];
    int t = threadIdx.x;
    int wave = t >> 6, lane = t & 63;
    int quad = lane >> 4, l16 = lane & 15;
    int m0 = blockIdx.y * 128, n0 = blockIdx.x * (NT*16);

    f32x4 acc[2][NT] = {};
    int ldrow = lane >> 2;
    int ldk   = (lane & 3) * 8;

    for (int k0 = 0; k0 < K; k0 += 32){
        #pragma unroll
        for (int s2 = 0; s2 < 2; ++s2){
            int s = wave*2 + s2;
            async16(A + (size_t)(m0 + s*16 + ldrow)*K + k0 + ldk, &As[s*512]);
        }
        #pragma unroll
        for (int i = 0; i < NT/4; ++i){
            async16(Bt + (size_t)(n0 + i*64 + wave*16 + ldrow)*K + k0 + ldk,
                    &Bs[i*2048 + wave*512]);
        }
        __syncthreads();
        bf16x8 af[2], bfr[NT];
        #pragma unroll
        for (int mt=0; mt<2; ++mt)
            af[mt] = *(const bf16x8*)&As[(wave*32 + mt*16 + l16)*32 + quad*8];
        #pragma unroll
        for (int nt=0; nt<NT; ++nt)
            bfr[nt] = *(const bf16x8*)&Bs[(nt*16 + l16)*32 + quad*8];
        #pragma unroll
        for (int mt=0; mt<2; ++mt)
            #pragma unroll
            for (int nt=0; nt<NT; ++nt)
                acc[mt][nt] = __builtin_amdgcn_mfma_f32_16x16x32_bf16(
                    af[mt], bfr[nt], acc[mt][nt], 0, 0, 0);
        __syncthreads();
    }

    float* Cf = (float*)Cout;
    unsigned short* Ch = (unsigned short*)Cout;
    #pragma unroll
    for (int mt=0; mt<2; ++mt){
        #pragma unroll
        for (int nt=0; nt<NT; ++nt){
            int n = n0 + nt*16 + l16;
            if (MODE==5 && n0 + nt*16 >= 384){
                int d = n - 384;
                int win = m0 >> 7;
                int tok0 = wave*32 + mt*16 + quad*4;
                float bn = bias[n];
                ushort4 vv;
                vv.x = f2bf(acc[mt][nt][0]+bn); vv.y = f2bf(acc[mt][nt][1]+bn);
                vv.z = f2bf(acc[mt][nt][2]+bn); vv.w = f2bf(acc[mt][nt][3]+bn);
                *(ushort4*)&Vout[((size_t)win*192 + d)*128 + tok0] = vv;
                continue;
            }
            #pragma unroll
            for (int r=0; r<4; ++r){
                int m = m0 + wave*32 + mt*16 + quad*4 + r;
                float v = acc[mt][nt][r] + bias[n];
                if (MODE==5){
                    Ch[(size_t)m*384 + n] = f2bf(v);
                } else if (MODE==6){
                    Ch[(size_t)m*768 + n] = f2bf(gelu_f(v));
                } else if (MODE==7){
                    Cf[(size_t)(m + row0)*CCH + n] += v;
                } else {
                    int mg = m + row0;
                    int wb = mg>>7, tok = mg&127;
                    int b = wb>>8, nw = wb&255;
                    int zs = (nw>>4)*2 + (tok>>6);
                    int hs = ((nw>>2)&3)*8 + ((tok>>3)&7);
                    int ws = (nw&3)*8 + (tok&7);
                    int z,h,w;
                    if (shifted){ z=(zs+1)&31; h=(hs+4)&31; w=(ws+4)&31; }
                    else        { z=zs; h=hs; w=ws; }
                    Cf[(size_t)(((b*32+z)*32+h)*32+w)*CCH + n] += v;
                }
            }
        }
    }
}

// ---------------- MFMA attention (unchanged from R6) -----------------------
__global__ __launch_bounds__(256) void attn_mfma(
    const unsigned short* __restrict__ qk,
    const unsigned short* __restrict__ vbuf,
    unsigned short* __restrict__ obuf,
    const unsigned short* __restrict__ bias_layer,
    int shifted, int wb0)
{
    __shared__ __align__(16) unsigned short Ks[4096];
    __shared__ __align__(16) unsigned short Vt[4096];
    __shared__ __align__(16) unsigned short Ps[16384];
    __shared__ float linv[128];
    __shared__ int grp[128];

    int t = threadIdx.x;
    int wave = t >> 6, lane = t & 63;
    int quad = lane >> 4, l16 = lane & 15;
    int wb = blockIdx.x / HEADS;
    int head = blockIdx.x % HEADS;
    int nw = (wb + wb0) & 255;

    const unsigned short* qkw = qk + (size_t)wb*128*384;

    bf16x8 af[2];
    #pragma unroll
    for (int mt=0; mt<2; ++mt)
        af[mt] = *(const bf16x8*)(qkw + (size_t)(wave*32 + mt*16 + l16)*384 + head*32 + quad*8);

    {
        int chunk = lane >> 4, low = lane & 15;
        #pragma unroll
        for (int i=0; i<2; ++i){
            int j = wave*2 + i;
            async16(qkw + (size_t)(j*16 + low)*384 + 192 + head*32 + chunk*8, &Ks[j*512]);
        }
        const unsigned short* vb = vbuf + ((size_t)wb*192 + head*32)*128;
        #pragma unroll
        for (int i=0; i<2; ++i){
            int j = wave*2 + i; int dgrp = j>>2, tg = j&3;
            async16(vb + (size_t)(dgrp*16 + low)*128 + tg*32 + chunk*8, &Vt[j*512]);
        }
        const unsigned short* bsrc = bias_layer + (size_t)head*16384;
        #pragma unroll
        for (int i=0; i<8; ++i){
            int j = wave*8 + i;
            async16(bsrc + j*512 + lane*8, &Ps[j*512]);
        }
    }
    if (t < 128 && shifted){
        int zs = (nw>>4)*2 + (t>>6);
        int hs = ((nw>>2)&3)*8 + ((t>>3)&7);
        int ws = (nw&3)*8 + (t&7);
        grp[t] = zone_z(zs)*9 + zone_hw(hs)*3 + zone_hw(ws);
    }
    __syncthreads();

    f32x4 sacc[2][8] = {};
    #pragma unroll
    for (int nt=0; nt<8; ++nt){
        bf16x8 bfr = *(const bf16x8*)&Ks[nt*512 + quad*128 + l16*8];
        sacc[0][nt] = __builtin_amdgcn_mfma_f32_16x16x32_bf16(af[0], bfr, sacc[0][nt], 0,0,0);
        sacc[1][nt] = __builtin_amdgcn_mfma_f32_16x16x32_bf16(af[1], bfr, sacc[1][nt], 0,0,0);
    }

    const float scale = 0.17677669529663689f;
    #pragma unroll
    for (int mt=0; mt<2; ++mt){
        #pragma unroll
        for (int r=0; r<4; ++r){
            int row = wave*32 + mt*16 + quad*4 + r;
            int rbase = (wave*2+mt)*2048 + (quad*4+r)*8;
            int myg = shifted ? grp[row] : 0;
            float sv[8]; int offv[8];
            float mloc = -1e30f;
            #pragma unroll
            for (int nt=0; nt<8; ++nt){
                int off = rbase + (nt>>1)*512 + (((nt&1)<<1) + (l16>>3))*128 + (l16&7);
                offv[nt] = off;
                float s = sacc[mt][nt][r]*scale + bf2f(Ps[off]);
                if (shifted && grp[nt*16+l16] != myg) s -= 100.f;
                sv[nt] = s;
                mloc = fmaxf(mloc, s);
            }
            #pragma unroll
            for (int off=1; off<16; off<<=1) mloc = fmaxf(mloc, __shfl_xor(mloc, off));
            float lloc = 0.f;
            #pragma unroll
            for (int nt=0; nt<8; ++nt){
                float p = __expf(sv[nt]-mloc);
                sv[nt] = p; lloc += p;
            }
            #pragma unroll
            for (int off=1; off<16; off<<=1) lloc += __shfl_xor(lloc, off);
            #pragma unroll
            for (int nt=0; nt<8; ++nt)
                Ps[offv[nt]] = f2bf(sv[nt]);
            if (l16==0) linv[row] = 1.f/lloc;
        }
    }

    f32x4 oacc[2][2] = {};
    #pragma unroll
    for (int ks=0; ks<4; ++ks){
        bf16x8 av0 = *(const bf16x8*)&Vt[         ks*512 + quad*128 + l16*8];
        bf16x8 av1 = *(const bf16x8*)&Vt[ 2048 +  ks*512 + quad*128 + l16*8];
        bf16x8 pf0 = *(const bf16x8*)&Ps[(wave*2+0)*2048 + ks*512 + quad*128 + l16*8];
        bf16x8 pf1 = *(const bf16x8*)&Ps[(wave*2+1)*2048 + ks*512 + quad*128 + l16*8];
        oacc[0][0] = __builtin_amdgcn_mfma_f32_16x16x32_bf16(av0, pf0, oacc[0][0], 0,0,0);
        oacc[0][1] = __builtin_amdgcn_mfma_f32_16x16x32_bf16(av1, pf0, oacc[0][1], 0,0,0);
        oacc[1][0] = __builtin_amdgcn_mfma_f32_16x16x32_bf16(av0, pf1, oacc[1][0], 0,0,0);
        oacc[1][1] = __builtin_amdgcn_mfma_f32_16x16x32_bf16(av1, pf1, oacc[1][1], 0,0,0);
    }

    #pragma unroll
    for (int mt=0; mt<2; ++mt){
        int token = wave*32 + mt*16 + l16;
        float inv = linv[token];
        unsigned short* dst = obuf + (size_t)(wb*128+token)*CCH + head*32;
        #pragma unroll
        for (int dt=0; dt<2; ++dt){
            ushort4 v4;
            v4.x = f2bf(oacc[mt][dt][0]*inv);
            v4.y = f2bf(oacc[mt][dt][1]*inv);
            v4.z = f2bf(oacc[mt][dt][2]*inv);
            v4.w = f2bf(oacc[mt][dt][3]*inv);
            *(ushort4*)&dst[dt*16 + quad*4] = v4;
        }
    }
}

extern "C" void kernel_launch(void* const* d_in, const int* in_sizes, int n_in,
                              void* d_out, int out_size, void* d_ws, size_t ws_size,
                              hipStream_t stream) {
    const float* x       = (const float*)d_in[0];
    const float* pe_w    = (const float*)d_in[1];
    const float* pe_b    = (const float*)d_in[2];
    const float* pe_ln_g = (const float*)d_in[3];
    const float* pe_ln_b = (const float*)d_in[4];
    const float* ln1_g   = (const float*)d_in[5];
    const float* ln1_b   = (const float*)d_in[6];
    const float* qkv_w   = (const float*)d_in[7];
    const float* qkv_b   = (const float*)d_in[8];
    const float* proj_w  = (const float*)d_in[9];
    const float* proj_b  = (const float*)d_in[10];
    const float* rpb     = (const float*)d_in[11];
    const float* ln2_g   = (const float*)d_in[12];
    const float* ln2_b   = (const float*)d_in[13];
    const float* fc1_w   = (const float*)d_in[14];
    const float* fc1_b   = (const float*)d_in[15];
    const float* fc2_w   = (const float*)d_in[16];
    const float* fc2_b   = (const float*)d_in[17];
    const float* rec_w   = (const float*)d_in[18];
    const float* rec_b   = (const float*)d_in[19];
    float* out = (float*)d_out;
    char* wsb = (char*)d_ws;

    float*          e        = (float*)wsb;
    unsigned short* bias_il  = (unsigned short*)(wsb + 50331648);
    unsigned short* wt       = (unsigned short*)(wsb + 51904512);
    unsigned short* pwb      = wt + 1769472;
    unsigned short* rwt      = wt + 1794048;
    char*           stage    = wsb + 55541760;
    size_t scap = ws_size > 55541760 ? ws_size - 55541760 : 0;

    int WCH = 512;
    while (WCH > 16 && (size_t)WCH*128*1920 > scap) WCH >>= 1;

    for (int d = 0; d < 4; ++d){
        unsigned short* wl = wt + (size_t)d*442368;
        wt_convert<<<(110592+255)/256, 256, 0, stream>>>(qkv_w  + (size_t)d*110592, wl,          192, 576);
        wt_convert<<<( 36864+255)/256, 256, 0, stream>>>(proj_w + (size_t)d* 36864, wl + 110592, 192, 192);
        wt_convert<<<(147456+255)/256, 256, 0, stream>>>(fc1_w  + (size_t)d*147456, wl + 147456, 192, 768);
        wt_convert<<<(147456+255)/256, 256, 0, stream>>>(fc2_w  + (size_t)d*147456, wl + 294912, 768, 192);
    }
    pe_conv<<<96, 256, 0, stream>>>(pe_w, pwb, 24576);
    wt_convert<<<96, 256, 0, stream>>>(rec_w, rwt, 192, 128);

    bias_precompute<<<24, 128, 0, stream>>>(rpb, bias_il);
    patch_embed_mfma<<<1024, 256, 0, stream>>>(x, pwb, pe_b, pe_ln_g, pe_ln_b, e);

    for (int d = 0; d < 4; ++d){
        int sh = d & 1;
        unsigned short* wl = wt + (size_t)d*442368;
        for (int w0 = 0; w0 < 512; w0 += WCH){
            int rows = WCH*128;
            unsigned short* bufc = (unsigned short*)stage;
            unsigned short* qkc  = (unsigned short*)(stage + (size_t)rows*384);
            unsigned short* vc   = (unsigned short*)(stage + (size_t)rows*1152);
            unsigned short* oc   = (unsigned short*)(stage + (size_t)rows*1536);
            ln_kernel<<<rows, 192, 0, stream>>>(
                e, bufc, ln1_g + d*CCH, ln1_b + d*CCH, sh, w0*128, 1);
            gemm_mfma<5,4><<<dim3(9, rows/128), 256, 0, stream>>>(
                bufc, wl, qkv_b + d*3*CCH, qkc, vc, 576, 192, 0, 0);
            attn_mfma<<<WCH*HEADS, 256, 0, stream>>>(
                qkc, vc, oc, bias_il + (size_t)d*HEADS*16384, sh, w0);
            gemm_mfma<2,4><<<dim3(3, rows/128), 256, 0, stream>>>(
                oc, wl + 110592, proj_b + d*CCH, e, nullptr, 192, 192, sh, w0*128);
        }
        // ---- MLP: ln2 -> fc1+gelu(h bf16, NT=8) -> fc2+residual (NT=12) ----
        for (int r0 = 0; r0 < 65536; r0 += WCH*128){
            int rows = WCH*128;
            unsigned short* abuf = (unsigned short*)stage;
            unsigned short* hbuf = (unsigned short*)(stage + (size_t)rows*384);
            ln_kernel<<<rows, 192, 0, stream>>>(
                e, abuf, ln2_g + d*CCH, ln2_b + d*CCH, 0, r0, 0);
            gemm_mfma<6,8><<<dim3(6, rows/128), 256, 0, stream>>>(
                abuf, wl + 147456, fc1_b + d*4*CCH, hbuf, nullptr, 768, 192, 0, 0);
            gemm_mfma<7,12><<<dim3(1, rows/128), 256, 0, stream>>>(
                hbuf, wl + 294912, fc2_b + d*CCH, e, nullptr, 192, 768, 0, r0);
        }
    }
    recon_mfma<<<1024, 256, 0, stream>>>(e, rwt, rec_b, out);
}